// Round 1
// baseline (118.142 us; speedup 1.0000x reference)
//
#include <hip/hip_runtime.h>
#include <hip/hip_fp16.h>

// Problem constants
constexpr int B_TOT = 8192;      // batch
constexpr int NM    = 64;        // n_models
constexpr int TT    = 16;        // trees per split
constexpr int LF    = 64;        // maxleaf
constexpr int EM    = 32;        // emb dim
constexpr int XROW  = NM * TT;   // 1024 ints per x row
constexpr int TROWS = TT * LF;   // 1024 rows per model table

// Broadcast quad-lane TQ's int4 to all 4 lanes of each quad via DPP
// (VALU pipe — does NOT load the LDS pipe like __shfl/ds_bpermute would).
template<int TQ>
__device__ __forceinline__ int4 qbcast(int4 v) {
    constexpr int c = TQ * 0x55;          // quad_perm [TQ,TQ,TQ,TQ]
    int4 r;
    r.x = __builtin_amdgcn_mov_dpp(v.x, c, 0xf, 0xf, true);
    r.y = __builtin_amdgcn_mov_dpp(v.y, c, 0xf, 0xf, true);
    r.z = __builtin_amdgcn_mov_dpp(v.z, c, 0xf, 0xf, true);
    r.w = __builtin_amdgcn_mov_dpp(v.w, c, 0xf, 0xf, true);
    return r;
}

__device__ __forceinline__ __half2 H2(unsigned u) { return *(const __half2*)&u; }

// ---------------------------------------------------------------------------
// K1: per-channel batch stats from an LDS-resident f16 table + f16 h spill.
// R8 changes:
//  (a) Bank-quad swizzle on the LDS table. Old layout tb[row*4+f] has
//      bank-quad = f + 4*(row&1): the 16 same-f lanes of a wave hit only
//      2 of 8 quads -> systematic conflicts on every gather b128. New
//      physical index row*4 + ((f ^ (row>>1)) & 3): quad-mates (same row)
//      stay disjoint, same-f lanes spread over all 8 quads.
//  (b) Spill h[b,m,:] as f16 (one uint4/thread/phase, coalesced 64B/quad).
//      out = dot(h,a)+C, so K3 becomes a barrier-free stream and K2 loses
//      its 8MB table re-read. Write hides under the LDS-bound gather.
// Block: 512 thr owns model m; 64KB f16 table in LDS; 8 phases x 128 b.
// LDS: 64 + 2 KB -> 2 blocks/CU (16 waves). Grid 512 = 64 m x 8 chunks.
// ---------------------------------------------------------------------------
__global__ __launch_bounds__(512, 4) void k_stats_f16(
    const int* __restrict__ x, const float* __restrict__ tbl,
    float* __restrict__ psum, float* __restrict__ psq,
    __half* __restrict__ h_out)
{
    __shared__ uint4 tb[TROWS * 4];      // 64KB f16 table, swizzled quads
    __shared__ float red[2][8][32];      // 2KB reduction scratch

    const int m     = blockIdx.x & 63;
    const int chunk = blockIdx.x >> 6;   // 0..7
    const int tid   = threadIdx.x;
    const int f     = tid & 3;           // channel quad (8 ch) AND t-quad owned
    const int grp   = tid >> 2;          // 0..127 = b within phase
    const int b0    = chunk * 1024;

    // ---- stage + convert table m: f32 128KB -> f16 64KB (4096 uint4) ----
    {
        const float4* __restrict__ src = (const float4*)(tbl + (size_t)m * (TROWS * EM));
#pragma unroll
        for (int i = 0; i < 8; ++i) {
            const int o = tid + i * 512;             // logical uint4 idx 0..4095
            const float4 a = src[o * 2];
            const float4 c = src[o * 2 + 1];
            uint4 p;
            __half2 h0 = __floats2half2_rn(a.x, a.y);
            __half2 h1 = __floats2half2_rn(a.z, a.w);
            __half2 h2 = __floats2half2_rn(c.x, c.y);
            __half2 h3 = __floats2half2_rn(c.z, c.w);
            p.x = *(unsigned*)&h0; p.y = *(unsigned*)&h1;
            p.z = *(unsigned*)&h2; p.w = *(unsigned*)&h3;
            // swizzle: row = o>>2, fq = o&3 -> (o & ~3) | ((fq ^ (row>>1)) & 3)
            const int sw = (o & ~3) | ((o ^ (o >> 3)) & 3);
            tb[sw] = p;                  // bijective per 4-group: write pattern
        }                                // identical to linear (conflict-free)
    }

    // ---- prefetch x for phase 0: ONE int4 per lane (t-quad f of b0+grp) ----
    int4 xr = ((const int4*)(x + (size_t)(b0 + grp) * XROW + m * TT))[f];

    float s[8], s2[8];
#pragma unroll
    for (int k = 0; k < 8; ++k) { s[k] = 0.f; s2[k] = 0.f; }

    // h spill base for this thread (phase p adds p*128 rows of b)
    __half* __restrict__ hp =
        h_out + ((size_t)(b0 + grp) * NM + m) * EM + f * 8;

    __syncthreads();                     // tb ready

    for (int p = 0; p < 8; ++p) {
        int4 nxt;
        if (p < 7)                       // next phase's x; hides behind gather
            nxt = ((const int4*)(x + (size_t)(b0 + (p + 1) * 128 + grp) * XROW + m * TT))[f];

        // all 16 tree indices of this quad's b, via quad broadcast
        const int4 q0 = qbcast<0>(xr);
        const int4 q1 = qbcast<1>(xr);
        const int4 q2 = qbcast<2>(xr);
        const int4 q3 = qbcast<3>(xr);

        __half2 h0 = __half2(__half(0.f), __half(0.f));
        __half2 h1 = h0, h2 = h0, h3 = h0;

        // swizzled physical index for (row r, quad f)
#define TIX(r) (((r) << 2) | ((f ^ ((r) >> 1)) & 3))
#define GATH(Q, RB)                                                          \
        {                                                                    \
            const uint4 a0 = tb[TIX((Q).x + RB      )];                      \
            const uint4 a1 = tb[TIX((Q).y + RB +  64)];                      \
            const uint4 a2 = tb[TIX((Q).z + RB + 128)];                      \
            const uint4 a3 = tb[TIX((Q).w + RB + 192)];                      \
            h0 = __hadd2(h0, __hadd2(__hadd2(H2(a0.x), H2(a1.x)),            \
                                     __hadd2(H2(a2.x), H2(a3.x))));          \
            h1 = __hadd2(h1, __hadd2(__hadd2(H2(a0.y), H2(a1.y)),            \
                                     __hadd2(H2(a2.y), H2(a3.y))));          \
            h2 = __hadd2(h2, __hadd2(__hadd2(H2(a0.z), H2(a1.z)),            \
                                     __hadd2(H2(a2.z), H2(a3.z))));          \
            h3 = __hadd2(h3, __hadd2(__hadd2(H2(a0.w), H2(a1.w)),            \
                                     __hadd2(H2(a2.w), H2(a3.w))));          \
        }
        GATH(q0, 0) GATH(q1, 256) GATH(q2, 512) GATH(q3, 768)
#undef GATH
#undef TIX

        // spill h (8 ch f16 = 16B, coalesced 64B per quad)
        {
            uint4 hv4;
            hv4.x = *(unsigned*)&h0; hv4.y = *(unsigned*)&h1;
            hv4.z = *(unsigned*)&h2; hv4.w = *(unsigned*)&h3;
            *(uint4*)(hp + (size_t)p * 128 * NM * EM) = hv4;
        }

        const __half2 hv[4] = {h0, h1, h2, h3};
#pragma unroll
        for (int k = 0; k < 4; ++k) {
            const float lo = __low2float(hv[k]);
            const float hi = __high2float(hv[k]);
            s[2*k]   += lo;  s2[2*k]   = fmaf(lo, lo, s2[2*k]);
            s[2*k+1] += hi;  s2[2*k+1] = fmaf(hi, hi, s2[2*k+1]);
        }
        xr = nxt;
    }

    // ---- reduce over grp: butterfly within wave (grp bits = lane 2..5) ----
#pragma unroll
    for (int off = 4; off <= 32; off <<= 1) {
#pragma unroll
        for (int k = 0; k < 8; ++k) {
            s[k]  += __shfl_xor(s[k],  off);
            s2[k] += __shfl_xor(s2[k], off);
        }
    }
    const int wave = tid >> 6;
    if ((tid & 63) < 4) {
#pragma unroll
        for (int k = 0; k < 8; ++k) {
            red[0][wave][f * 8 + k] = s[k];
            red[1][wave][f * 8 + k] = s2[k];
        }
    }
    __syncthreads();
    if (tid < 32) {
        float a = 0.f, a2 = 0.f;
#pragma unroll
        for (int w = 0; w < 8; ++w) { a += red[0][w][tid]; a2 += red[1][w][tid]; }
        psum[(chunk * NM + m) * EM + tid] = a;   // per-(chunk,m) partials:
        psq [(chunk * NM + m) * EM + tid] = a2;  // no atomics, no memset
    }
}

// ---------------------------------------------------------------------------
// K2: finalize stats only (no table re-read, no g2):
//   a[m,e] = istd*gamma*w;  Cm[m] = bout_b[m] + sum_e (beta - mean*istd*gamma)*w
// Grid: 8 blocks x 256 thr = 2048 channels.
// ---------------------------------------------------------------------------
__global__ __launch_bounds__(256) void k_prep2(
    const float* __restrict__ gamma, const float* __restrict__ beta,
    const float* __restrict__ bw, const float* __restrict__ bb,
    const float* __restrict__ psum, const float* __restrict__ psq,
    float* __restrict__ ag, float* __restrict__ Cm)
{
    const int ch = blockIdx.x * 256 + threadIdx.x;   // 0..2047
    const int m  = ch >> 5;
    const int e  = ch & 31;
    float sum = 0.f, sq = 0.f;
#pragma unroll
    for (int c = 0; c < 8; ++c) {
        sum += psum[c * (NM * EM) + ch];
        sq  += psq [c * (NM * EM) + ch];
    }
    const float inv_n = 1.f / (float)B_TOT;
    const float mean  = sum * inv_n;
    const float var   = sq * inv_n - mean * mean;
    const float gi    = gamma[ch] * rsqrtf(var + 1e-5f);   // istd*gamma
    const float w     = bw[ch];
    ag[ch] = gi * w;
    float ct = (beta[ch] - mean * gi) * w;
#pragma unroll
    for (int off = 16; off > 0; off >>= 1) ct += __shfl_down(ct, off, 32);
    if (e == 0) Cm[m] = bb[m] + ct;
}

// ---------------------------------------------------------------------------
// K3: pure stream: out[b,m] = dot(h[b,m,:], a[m,:]) + C[m]; plus row sum.
// No x re-read, no g2 slab, no mid-kernel barriers. Wave = 64 m-lanes,
// 4 b per wave (16 uint4 global loads/lane = 256B, fully-used 64B lines).
// a in LDS padded [64][33]: bank (lane+e)%32 -> 2 lanes/bank = free.
// Grid: 512 blocks x 256 thr (16 b per block).
// ---------------------------------------------------------------------------
__global__ __launch_bounds__(256) void k_out2(
    const __half* __restrict__ h, const float* __restrict__ ag,
    const float* __restrict__ Cm, float* __restrict__ out)
{
    __shared__ float a_s[NM][EM + 1];
    __shared__ float c_s[NM];
    const int tid = threadIdx.x;
#pragma unroll
    for (int i = 0; i < 8; ++i) {
        const int o = tid + i * 256;                 // 0..2047
        a_s[o >> 5][o & 31] = ag[o];
    }
    if (tid < NM) c_s[tid] = Cm[tid];
    __syncthreads();

    const int lane = tid & 63;                       // = m
    const int wv   = tid >> 6;                       // 0..3
    const int b0   = blockIdx.x * 16 + wv * 4;       // 4 b per wave

    const uint4* __restrict__ hp =
        (const uint4*)(h) + ((size_t)b0 * NM + lane) * (EM / 8);

    uint4 v[4][4];
#pragma unroll
    for (int j = 0; j < 4; ++j)                      // b stride = NM*EM/8 = 256
#pragma unroll
        for (int k = 0; k < 4; ++k)
            v[j][k] = hp[j * 256 + k];

    float ob[4] = {0.f, 0.f, 0.f, 0.f};
#pragma unroll
    for (int j = 0; j < 4; ++j) {
#pragma unroll
        for (int k = 0; k < 4; ++k) {
            const float2 f0 = __half22float2(H2(v[j][k].x));
            const float2 f1 = __half22float2(H2(v[j][k].y));
            const float2 f2 = __half22float2(H2(v[j][k].z));
            const float2 f3 = __half22float2(H2(v[j][k].w));
            const int e = k * 8;
            ob[j] = fmaf(f0.x, a_s[lane][e + 0], ob[j]);
            ob[j] = fmaf(f0.y, a_s[lane][e + 1], ob[j]);
            ob[j] = fmaf(f1.x, a_s[lane][e + 2], ob[j]);
            ob[j] = fmaf(f1.y, a_s[lane][e + 3], ob[j]);
            ob[j] = fmaf(f2.x, a_s[lane][e + 4], ob[j]);
            ob[j] = fmaf(f2.y, a_s[lane][e + 5], ob[j]);
            ob[j] = fmaf(f3.x, a_s[lane][e + 6], ob[j]);
            ob[j] = fmaf(f3.y, a_s[lane][e + 7], ob[j]);
        }
    }

#pragma unroll
    for (int j = 0; j < 4; ++j) {
        const float o = ob[j] + c_s[lane];
        float s = o;
#pragma unroll
        for (int off = 32; off > 0; off >>= 1) s += __shfl_down(s, off);
        out[B_TOT + (size_t)(b0 + j) * NM + lane] = o;   // out tensor (B, M)
        if (lane == 0) out[b0 + j] = s;                  // sum_out (B, 1)
    }
}

// ---------------------------------------------------------------------------
extern "C" void kernel_launch(void* const* d_in, const int* in_sizes, int n_in,
                              void* d_out, int out_size, void* d_ws, size_t ws_size,
                              hipStream_t stream) {
    const int*   x       = (const int*)d_in[0];
    const float* embed_w = (const float*)d_in[1];
    const float* gamma   = (const float*)d_in[2];
    const float* beta    = (const float*)d_in[3];
    const float* bout_w  = (const float*)d_in[4];
    const float* bout_b  = (const float*)d_in[5];
    float* out = (float*)d_out;

    // workspace layout: h (32MB f16) | psum | psq | ag | Cm
    __half* h    = (__half*)d_ws;
    float*  ws   = (float*)d_ws + ((size_t)B_TOT * NM * EM / 2);  // after 32MB
    float* psum  = ws;                        // 8 x 64 x 32 = 16384
    float* psq   = psum + 16384;              // 16384
    float* ag    = psq + 16384;               // 2048
    float* Cm    = ag + 2048;                 // 64

    k_stats_f16<<<dim3(512), dim3(512), 0, stream>>>(x, embed_w, psum, psq, h);
    k_prep2   <<<dim3(8),   dim3(256), 0, stream>>>(gamma, beta, bout_w, bout_b,
                                                    psum, psq, ag, Cm);
    k_out2    <<<dim3(512), dim3(256), 0, stream>>>(h, ag, Cm, out);
}

// Round 4
// 112.581 us; speedup vs baseline: 1.0494x; 1.0494x over previous
//
#include <hip/hip_runtime.h>
#include <hip/hip_fp16.h>

// Problem constants
constexpr int B_TOT = 8192;      // batch
constexpr int NM    = 64;        // n_models
constexpr int TT    = 16;        // trees per split
constexpr int LF    = 64;        // maxleaf
constexpr int EM    = 32;        // emb dim
constexpr int XROW  = NM * TT;   // 1024 ints per x row
constexpr int TROWS = TT * LF;   // 1024 rows per model table

// Broadcast quad-lane TQ's int4 to all 4 lanes of each quad via DPP
// (VALU pipe — does NOT load the LDS pipe like __shfl/ds_bpermute would).
template<int TQ>
__device__ __forceinline__ int4 qbcast(int4 v) {
    constexpr int c = TQ * 0x55;          // quad_perm [TQ,TQ,TQ,TQ]
    int4 r;
    r.x = __builtin_amdgcn_mov_dpp(v.x, c, 0xf, 0xf, true);
    r.y = __builtin_amdgcn_mov_dpp(v.y, c, 0xf, 0xf, true);
    r.z = __builtin_amdgcn_mov_dpp(v.z, c, 0xf, 0xf, true);
    r.w = __builtin_amdgcn_mov_dpp(v.w, c, 0xf, 0xf, true);
    return r;
}

__device__ __forceinline__ __half2 H2(unsigned u) { return *(const __half2*)&u; }

// ---------------------------------------------------------------------------
// K1: per-channel batch stats from an LDS-resident f16 table.
// R4 change (vs proven R0): the f16 table is stored as TWO 8B-element
// arrays (low ch 0-3 / high ch 4-7 of each f-quad) instead of one 16B
// array. Conflict model: b128 on 16B elements gives bank = (16row+4f)%32
// -> row contributes ONE bank bit -> ~8 rows/bank = 8-way (2.94x, m136).
// 8B elements give bank = (8row+2f)%32 -> row gives TWO bank bits ->
// collisions only for row==row' (mod 4) -> 4-way (1.58x). Each gather is
// two ds_read_b64 on one vaddr (offsets 0 / 32768), same bytes as before.
// Block: 512 thr owns model m; 64+2KB LDS -> 2 blocks/CU (16 waves).
// Grid 512 = 64 m x 8 chunks; 8 phases x 128 b.
// ---------------------------------------------------------------------------
__global__ __launch_bounds__(512, 4) void k_stats_f16(
    const int* __restrict__ x, const float* __restrict__ tbl,
    float* __restrict__ psum, float* __restrict__ psq)
{
    __shared__ uint2 tbS[2][TROWS * 4];  // 2 x 32KB: [half][row*4+f]
    __shared__ float red[2][8][32];      // 2KB reduction scratch

    const int m     = blockIdx.x & 63;
    const int chunk = blockIdx.x >> 6;   // 0..7
    const int tid   = threadIdx.x;
    const int f     = tid & 3;           // channel quad (8 ch) AND t-quad owned
    const int grp   = tid >> 2;          // 0..127 = b within phase
    const int b0    = chunk * 1024;

    // ---- stage + convert table m: f32 128KB -> f16 2x32KB (split halves) ----
    {
        const float4* __restrict__ src = (const float4*)(tbl + (size_t)m * (TROWS * EM));
#pragma unroll
        for (int i = 0; i < 8; ++i) {
            const int o = tid + i * 512;             // element idx 0..4095 = row*4+fq
            const float4 a = src[o * 2];
            const float4 c = src[o * 2 + 1];
            __half2 h0 = __floats2half2_rn(a.x, a.y);
            __half2 h1 = __floats2half2_rn(a.z, a.w);
            __half2 h2 = __floats2half2_rn(c.x, c.y);
            __half2 h3 = __floats2half2_rn(c.z, c.w);
            uint2 lo, hi;
            lo.x = *(unsigned*)&h0; lo.y = *(unsigned*)&h1;   // ch 0-3 of quad
            hi.x = *(unsigned*)&h2; hi.y = *(unsigned*)&h3;   // ch 4-7 of quad
            tbS[0][o] = lo;
            tbS[1][o] = hi;
        }
    }

    // ---- prefetch x for phase 0: ONE int4 per lane (t-quad f of b0+grp) ----
    int4 xr = ((const int4*)(x + (size_t)(b0 + grp) * XROW + m * TT))[f];

    float s[8], s2[8];
#pragma unroll
    for (int k = 0; k < 8; ++k) { s[k] = 0.f; s2[k] = 0.f; }

    __syncthreads();                     // table ready

    for (int p = 0; p < 8; ++p) {
        int4 nxt = xr;
        if (p < 7)                       // next phase's x; hides behind gather
            nxt = ((const int4*)(x + (size_t)(b0 + (p + 1) * 128 + grp) * XROW + m * TT))[f];

        // all 16 tree indices of this quad's b, via quad broadcast
        const int4 q0 = qbcast<0>(xr);
        const int4 q1 = qbcast<1>(xr);
        const int4 q2 = qbcast<2>(xr);
        const int4 q3 = qbcast<3>(xr);

        __half2 h0 = __half2(__half(0.f), __half(0.f));
        __half2 h1 = h0, h2 = h0, h3 = h0;

        // one row: ix = row*4+f; two b64 reads (one vaddr, offset 0 / 32768)
#define ROWADD(R)                                                            \
        {                                                                    \
            const int ix = ((R) << 2) | f;                                   \
            const uint2 lo = tbS[0][ix];                                     \
            const uint2 hi = tbS[1][ix];                                     \
            h0 = __hadd2(h0, H2(lo.x));                                      \
            h1 = __hadd2(h1, H2(lo.y));                                      \
            h2 = __hadd2(h2, H2(hi.x));                                      \
            h3 = __hadd2(h3, H2(hi.y));                                      \
        }
        ROWADD(q0.x)        ROWADD(q0.y +  64) ROWADD(q0.z + 128) ROWADD(q0.w + 192)
        ROWADD(q1.x + 256)  ROWADD(q1.y + 320) ROWADD(q1.z + 384) ROWADD(q1.w + 448)
        ROWADD(q2.x + 512)  ROWADD(q2.y + 576) ROWADD(q2.z + 640) ROWADD(q2.w + 704)
        ROWADD(q3.x + 768)  ROWADD(q3.y + 832) ROWADD(q3.z + 896) ROWADD(q3.w + 960)
#undef ROWADD

        const __half2 hv[4] = {h0, h1, h2, h3};
#pragma unroll
        for (int k = 0; k < 4; ++k) {
            const float lo = __low2float(hv[k]);
            const float hi = __high2float(hv[k]);
            s[2*k]   += lo;  s2[2*k]   = fmaf(lo, lo, s2[2*k]);
            s[2*k+1] += hi;  s2[2*k+1] = fmaf(hi, hi, s2[2*k+1]);
        }
        xr = nxt;
    }

    // ---- reduce over grp: butterfly within wave (grp bits = lane 2..5) ----
#pragma unroll
    for (int off = 4; off <= 32; off <<= 1) {
#pragma unroll
        for (int k = 0; k < 8; ++k) {
            s[k]  += __shfl_xor(s[k],  off);
            s2[k] += __shfl_xor(s2[k], off);
        }
    }
    const int wave = tid >> 6;
    if ((tid & 63) < 4) {
#pragma unroll
        for (int k = 0; k < 8; ++k) {
            red[0][wave][f * 8 + k] = s[k];
            red[1][wave][f * 8 + k] = s2[k];
        }
    }
    __syncthreads();
    if (tid < 32) {
        float a = 0.f, a2 = 0.f;
#pragma unroll
        for (int w = 0; w < 8; ++w) { a += red[0][w][tid]; a2 += red[1][w][tid]; }
        psum[(chunk * NM + m) * EM + tid] = a;   // per-(chunk,m) partials:
        psq [(chunk * NM + m) * EM + tid] = a2;  // no atomics, no memset
    }
}

// ---------------------------------------------------------------------------
// K2: sum the 8 chunk-partials, fold BN + projection:
//   a[m,e]=istd*gamma*w; C[m]=bout_b[m]+sum_e (beta-mean*istd*gamma)*w
//   g2h[(t*64+leaf)*64+m] = (f16) dot(tbl[m,row,:], a[m,:])
// f16 g2 (R4): halves K3's slab traffic; quantization err ~1e-3 << 0.9 thr.
// Grid: 256 blocks = 64 m x 4 row-quarters, 256 threads.
// ---------------------------------------------------------------------------
__global__ __launch_bounds__(256) void k_prep(
    const float* __restrict__ tbl,
    const float* __restrict__ gamma, const float* __restrict__ beta,
    const float* __restrict__ bw, const float* __restrict__ bb,
    const float* __restrict__ psum, const float* __restrict__ psq,
    float* __restrict__ Cm, __half* __restrict__ g2h)
{
    const int m    = blockIdx.x >> 2;
    const int part = blockIdx.x & 3;
    __shared__ float a_s[EM];
    if (threadIdx.x < EM) {
        const int e  = threadIdx.x;
        const int ch = m * EM + e;
        float sum = 0.f, sq = 0.f;
#pragma unroll
        for (int c = 0; c < 8; ++c) {
            sum += psum[(c * NM + m) * EM + e];
            sq  += psq [(c * NM + m) * EM + e];
        }
        const float inv_n = 1.f / (float)B_TOT;
        const float mean = sum * inv_n;
        const float var  = sq * inv_n - mean * mean;
        const float istd = rsqrtf(var + 1e-5f);
        const float g = gamma[ch];
        const float w = bw[ch];
        a_s[e] = istd * g * w;
        float ct = (beta[ch] - mean * istd * g) * w;
#pragma unroll
        for (int off = 16; off > 0; off >>= 1) ct += __shfl_down(ct, off, 32);
        if (e == 0 && part == 0) Cm[m] = bb[m] + ct;
    }
    __syncthreads();

    const float* __restrict__ tblm = tbl + (size_t)m * (TROWS * EM);
    const int row = part * 256 + threadIdx.x;
    const float4* rp = (const float4*)(tblm + row * EM);
    float acc = 0.f;
#pragma unroll
    for (int i = 0; i < 8; ++i) {
        const float4 v = rp[i];
        acc += v.x * a_s[i*4+0] + v.y * a_s[i*4+1]
             + v.z * a_s[i*4+2] + v.w * a_s[i*4+3];
    }
    g2h[row * NM + m] = __float2half(acc);
}

// ---------------------------------------------------------------------------
// K3: out[b,m] = C[m] + sum_t g2h[(t*64 + x[b,m*16+t])*64 + m]; plus row sum.
// R4: f16 slab -> 64KB covers HALF of g2 (8 trees) -> 2 phases / 3 syncs
// (was 4 phases / 8) and 64MB aggregate staging (was 128MB). Gather bank =
// lane>>1 -> 2 lanes/bank = free (m136).
// Grid: 512 blocks x 1024 threads (16 b per block), 2 blocks/CU.
// ---------------------------------------------------------------------------
__global__ __launch_bounds__(1024, 8) void k_out(
    const int* __restrict__ x, const __half* __restrict__ g2h,
    const float* __restrict__ Cm, float* __restrict__ out)
{
    __shared__ __half slab[8 * LF * NM];     // 64KB = trees [8][leaf][m]
    const int tid  = threadIdx.x;
    const int wid  = tid >> 6;               // 0..15
    const int lane = tid & 63;               // = m
    const int b    = blockIdx.x * 16 + wid;

    const int4* xp = (const int4*)(x + (size_t)b * XROW + lane * TT);
    const int4 q0 = xp[0], q1 = xp[1], q2 = xp[2], q3 = xp[3];
    const int idxs[16] = {q0.x,q0.y,q0.z,q0.w, q1.x,q1.y,q1.z,q1.w,
                          q2.x,q2.y,q2.z,q2.w, q3.x,q3.y,q3.z,q3.w};

    float acc = 0.f;
#pragma unroll
    for (int ph = 0; ph < 2; ++ph) {
        if (ph) __syncthreads();             // done reading previous slab
        const uint4* src = (const uint4*)(g2h + (size_t)ph * (8 * LF * NM));
        uint4* dst = (uint4*)slab;
#pragma unroll
        for (int j = 0; j < 4; ++j) dst[tid + j * 1024] = src[tid + j * 1024];
        __syncthreads();
#pragma unroll
        for (int tt = 0; tt < 8; ++tt)
            acc += __half2float(slab[tt * (LF * NM) + idxs[ph * 8 + tt] * NM + lane]);
    }

    const float o = acc + Cm[lane];
    float s = o;
#pragma unroll
    for (int off = 32; off > 0; off >>= 1) s += __shfl_down(s, off);
    out[B_TOT + (size_t)b * NM + lane] = o;  // out tensor (B, M)
    if (lane == 0) out[b] = s;               // sum_out (B, 1)
}

// ---------------------------------------------------------------------------
extern "C" void kernel_launch(void* const* d_in, const int* in_sizes, int n_in,
                              void* d_out, int out_size, void* d_ws, size_t ws_size,
                              hipStream_t stream) {
    const int*   x       = (const int*)d_in[0];
    const float* embed_w = (const float*)d_in[1];
    const float* gamma   = (const float*)d_in[2];
    const float* beta    = (const float*)d_in[3];
    const float* bout_w  = (const float*)d_in[4];
    const float* bout_b  = (const float*)d_in[5];
    float* out = (float*)d_out;

    float* ws   = (float*)d_ws;
    float* psum = ws;                     // 8 chunks x 64 m x 32 e = 16384
    float* psq  = psum + 16384;           // 16384
    float* Cm   = psq + 16384;            // 64 (+pad to keep g2h 16B-aligned)
    __half* g2h = (__half*)(ws + 16384 + 16384 + 64);  // byte off 131328, %16==0

    k_stats_f16<<<dim3(512), dim3(512), 0, stream>>>(x, embed_w, psum, psq);
    k_prep<<<dim3(256), dim3(256),  0, stream>>>(embed_w, gamma, beta, bout_w,
                                                 bout_b, psum, psq, Cm, g2h);
    k_out <<<dim3(512), dim3(1024), 0, stream>>>(x, g2h, Cm, out);
}